// Round 8
// baseline (44.906 us; speedup 1.0000x reference)
//
#include <hip/hip_runtime.h>
#include <stdint.h>

// FusedFP4Linear: out = gelu(x @ dequant(w_fp4)^T + bias)
// M=128, K=4096, N=16384. Weights [N, K/2] int32, low byte = two FP4 nibbles
// (hi nibble = even k, lo nibble = odd k).
// R8: TWO independent barrier chains per CU. Block = 64x64 (M-split), grid
// 512 = 2 blocks/CU (64KB LDS each). Twin M-blocks share B via same-XCD
// swizzle (n_idx=(bid&7)*32+(bid>>4), mblk=(bid>>3)&1). Counted-vmcnt
// pipeline kept: NBUF=4, A depth-3 via gl16 (pre-swizzled src), B depth-4
// global->reg->decode-once->LDS. FIFO-trace-verified waits: steady vmcnt(8),
// prologue 8/10/10, tail 8/6/4/4/2/0.

#define M_DIM 128
#define K_DIM 4096
#define N_DIM 16384
#define BN    64
#define BK    64
#define NK    (K_DIM/BK)       // 64
#define NT    256              // 4 waves
#define NBLK  512              // 2 m-blocks x 256 n-tiles

#define A_BYTES 8192           // 64 rows x 128B bf16
#define B_BYTES 8192           // 64 rows x 128B bf16 (decoded)
#define NBUF    4
#define AOFF(b) ((b)*A_BYTES)
#define BOFF(b) (NBUF*A_BYTES + (b)*B_BYTES)
#define LDS_SZ  (NBUF*(A_BYTES+B_BYTES))   // 65536 -> 2 blocks/CU

typedef __attribute__((ext_vector_type(8))) __bf16 bf16x8;
typedef __attribute__((ext_vector_type(4))) float  f32x4;
typedef unsigned short ushort_t;

__device__ __forceinline__ unsigned f2b_bits(float f) {
  unsigned u = __builtin_bit_cast(unsigned, f);
  u += 0x7FFFu + ((u >> 16) & 1u);   // RNE
  return u >> 16;
}

__global__ __launch_bounds__(256) void convert_x_kernel(
    const float* __restrict__ x, ushort_t* __restrict__ xb) {
  int i = (blockIdx.x * blockDim.x + threadIdx.x) * 4;
  float4 v = *(const float4*)(x + i);
  ushort4 p;
  p.x = (ushort_t)f2b_bits(v.x);
  p.y = (ushort_t)f2b_bits(v.y);
  p.z = (ushort_t)f2b_bits(v.z);
  p.w = (ushort_t)f2b_bits(v.w);
  *(ushort4*)(xb + i) = p;
}

__device__ __forceinline__ void gl16(const void* g, void* l) {
  __builtin_amdgcn_global_load_lds(
      (const __attribute__((address_space(1))) void*)g,
      (__attribute__((address_space(3))) void*)l, 16, 0, 0);
}

// 4 packed int32 (low bytes) -> 8 bf16 (k-order: b0.hi, b0.lo, b1.hi, ...)
__device__ __forceinline__ bf16x8 decode8(uint4 p) {
  unsigned u01 = __builtin_amdgcn_perm(p.y, p.x, 0x04000400u);
  unsigned u23 = __builtin_amdgcn_perm(p.w, p.z, 0x04000400u);
  unsigned q   = __builtin_amdgcn_perm(u23, u01, 0x05040100u);  // [x0,y0,z0,w0]
  unsigned e  = (q >> 4) & 0x0F0F0F0Fu;    // even-k nibbles
  unsigned o  = q & 0x0F0F0F0Fu;           // odd-k nibbles
  unsigned em = e & 0x07070707u, om = o & 0x07070707u;
  unsigned elo = __builtin_amdgcn_perm(0xC0804000u, 0xC0800000u, em);
  unsigned ehi = __builtin_amdgcn_perm(0x40404040u, 0x3F3F3F00u, em);
  unsigned olo = __builtin_amdgcn_perm(0xC0804000u, 0xC0800000u, om);
  unsigned ohi = __builtin_amdgcn_perm(0x40404040u, 0x3F3F3F00u, om);
  ehi |= (e & 0x08080808u) << 4;           // sign -> bit7 of high byte
  ohi |= (o & 0x08080808u) << 4;
  unsigned t0 = __builtin_amdgcn_perm(ehi, elo, 0x05010400u);
  unsigned t1 = __builtin_amdgcn_perm(ohi, olo, 0x05010400u);
  unsigned t2 = __builtin_amdgcn_perm(ehi, elo, 0x07030602u);
  unsigned t3 = __builtin_amdgcn_perm(ohi, olo, 0x07030602u);
  uint4 r;
  r.x = __builtin_amdgcn_perm(t1, t0, 0x05040100u);
  r.y = __builtin_amdgcn_perm(t1, t0, 0x07060302u);
  r.z = __builtin_amdgcn_perm(t3, t2, 0x05040100u);
  r.w = __builtin_amdgcn_perm(t3, t2, 0x07060302u);
  return __builtin_bit_cast(bf16x8, r);
}

#define MFMA16(a_, b_, c_) __builtin_amdgcn_mfma_f32_16x16x32_bf16(a_, b_, c_, 0, 0, 0)

template<bool USE_XB>
__global__ __launch_bounds__(NT) void fp4gemm_kernel(
    const void* __restrict__ xsrc,        // bf16 xb (ws) or fp32 x
    const int*  __restrict__ wq,          // [N, K/2] packed
    const float* __restrict__ scale,      // [N]
    const float* __restrict__ bias,       // [N]
    float* __restrict__ out) {            // [M, N]
  __shared__ __align__(16) uint8_t lds[LDS_SZ];

  const int t   = threadIdx.x;
  const int w   = t >> 6;                 // wave 0..3
  const int l   = t & 63;
  const int l16 = l & 15;
  const int lq  = l >> 4;
  const int mq2 = w >> 1;                 // wave m-half within block (0..1)
  const int nh  = w & 1;                  // wave n-half (0..1)

  // twin-colocated, n-chunked XCD swizzle:
  //   xcd = bid&7 ; n_idx = (bid&7)*32 + (bid>>4) ; mblk = (bid>>3)&1
  // twins (same n, both mblk) share low-3 bits -> same XCD -> B via L2.
  const int bid  = blockIdx.x;
  const int n0   = ((bid & 7) * 32 + (bid >> 4)) * BN;
  const int mblk = (bid >> 3) & 1;        // rows mblk*64..+63

  // staging geometry: 256 thr x 16B = 4KB = 32 rows x 128B per round
  const int r0   = t >> 3;                // 0..31
  const int scol = (t & 7) * 16;          // byte col 0..112
  const int swz0 = (r0 & 7) << 4;
  const int scbs = scol ^ swz0;           // pre-swizzled source col (A)
  const int bwr0 = r0 * 128 + (scol ^ swz0);        // B ds_write (rows 0..31)
  const int bwr1 = bwr0 + 32 * 128;                 // rows 32..63 (same swz)

  const uint8_t* xb  = (const uint8_t*)xsrc;  // bf16 row = 8192 B
  const uint8_t* wqb = (const uint8_t*)wq;    // int32 row = 8192 B
  const size_t aRowBase = (size_t)(mblk * 64) * 8192;

  uint4 rq0a, rq0b, rq1a, rq1b, rq2a, rq2b, rq3a, rq3b;  // B reg slots

#define ISSUE_A(k_, b_) do { \
  gl16(xb + aRowBase + (size_t)(r0) * 8192 + (size_t)(k_) * 128 + scbs, \
       lds + AOFF(b_) + w * 1024); \
  gl16(xb + aRowBase + (size_t)(32 + r0) * 8192 + (size_t)(k_) * 128 + scbs, \
       lds + AOFF(b_) + 4096 + w * 1024); \
} while (0)

#define ISSUE_B(k_, s_) do { \
  rq##s_##a = *(const uint4*)(wqb + (size_t)(n0 + r0) * 8192 + \
                              (size_t)(k_) * 128 + scol); \
  rq##s_##b = *(const uint4*)(wqb + (size_t)(n0 + 32 + r0) * 8192 + \
                              (size_t)(k_) * 128 + scol); \
} while (0)

#define DECODE_B(s_) do { \
  *(bf16x8*)(lds + BOFF(s_) + bwr0) = decode8(rq##s_##a); \
  *(bf16x8*)(lds + BOFF(s_) + bwr1) = decode8(rq##s_##b); \
} while (0)

#define WAITV(N_) asm volatile("s_waitcnt vmcnt(" #N_ ")" ::: "memory")
#define BARRIER() do { \
  asm volatile("s_waitcnt lgkmcnt(0)" ::: "memory"); \
  __builtin_amdgcn_s_barrier(); \
  __builtin_amdgcn_sched_barrier(0); \
} while (0)

  f32x4 acc00 = {0,0,0,0}, acc01 = {0,0,0,0};
  f32x4 acc10 = {0,0,0,0}, acc11 = {0,0,0,0};

  const int aR0 = (mq2 * 32 + l16) * 128;      // A frag row base; +2048 fr=1
  const int bR0 = (nh  * 32 + l16) * 128;      // B frag row base; +2048 c=1
  const int cB  = (lq << 4) ^ ((l16 & 7) << 4);

#define COMPUTE(b_) do { \
  const uint8_t* Ab_ = lds + AOFF(b_); \
  const uint8_t* Bb_ = lds + BOFF(b_); \
  _Pragma("unroll") \
  for (int ks_ = 0; ks_ < 2; ++ks_) { \
    const int cS_ = (ks_ << 6) ^ cB; \
    bf16x8 a0_ = *(const bf16x8*)(Ab_ + aR0 + cS_); \
    bf16x8 a1_ = *(const bf16x8*)(Ab_ + aR0 + 2048 + cS_); \
    bf16x8 b0_ = *(const bf16x8*)(Bb_ + bR0 + cS_); \
    bf16x8 b1_ = *(const bf16x8*)(Bb_ + bR0 + 2048 + cS_); \
    acc00 = MFMA16(a0_, b0_, acc00); \
    acc01 = MFMA16(a0_, b1_, acc01); \
    acc10 = MFMA16(a1_, b0_, acc10); \
    acc11 = MFMA16(a1_, b1_, acc11); \
  } \
} while (0)

// BODY(k): wait A(k)+B(k+3); barrier; decode B(k+2) (slot (k+2)&3) -> LDS;
// issue B(k+6) -> same slot; issue A(k+3) -> buf (k+3)&3; compute tile k.
#define BODY(k_, s_, ab_, cb_) do { \
  WAITV(8); \
  BARRIER(); \
  DECODE_B(s_); \
  ISSUE_B((k_) + 6, s_); \
  ISSUE_A((k_) + 3, ab_); \
  COMPUTE(cb_); \
} while (0)

  if constexpr (USE_XB) {
    // ---- prologue (FIFO-trace verified) ----
    ISSUE_B(0, 0); ISSUE_B(1, 1); ISSUE_B(2, 2); ISSUE_B(3, 3);   // 8 ops
    ISSUE_A(0, 0); ISSUE_A(1, 1); ISSUE_A(2, 2);                  // 6 ops
    WAITV(6);                      // B0..B3 landed
    DECODE_B(0); DECODE_B(1);
    ISSUE_B(4, 0); ISSUE_B(5, 1);  // outstanding 10
    // kt=0
    WAITV(8);  BARRIER(); DECODE_B(2); ISSUE_B(6, 2); ISSUE_A(3, 3); COMPUTE(0);
    // kt=1
    WAITV(10); BARRIER(); DECODE_B(3); ISSUE_B(7, 3); ISSUE_A(4, 0); COMPUTE(1);
    // kt=2
    WAITV(10); BARRIER(); DECODE_B(0); ISSUE_B(8, 0); ISSUE_A(5, 1); COMPUTE(2);
    // kt=3..5 (steady entry)
    BODY(3, 1, 2, 3);
    BODY(4, 2, 3, 0);
    BODY(5, 3, 0, 1);
    // ---- main loop: kt = 6..57 (13 x 4) ----
    for (int j = 0; j < 13; ++j) {
      const int kt = 6 + 4 * j;
      BODY(kt + 0, 0, 1, 2);
      BODY(kt + 1, 1, 2, 3);
      BODY(kt + 2, 2, 3, 0);
      BODY(kt + 3, 3, 0, 1);
    }
    // ---- tail ----
    WAITV(8); BARRIER(); DECODE_B(0); ISSUE_A(61, 1); COMPUTE(2);  // kt=58
    WAITV(6); BARRIER(); DECODE_B(1); ISSUE_A(62, 2); COMPUTE(3);  // kt=59
    WAITV(4); BARRIER(); DECODE_B(2); ISSUE_A(63, 3); COMPUTE(0);  // kt=60
    WAITV(4); BARRIER(); DECODE_B(3); COMPUTE(1);                  // kt=61
    WAITV(2); BARRIER(); COMPUTE(2);                               // kt=62
    WAITV(0); BARRIER(); COMPUTE(3);                               // kt=63
  } else {
    // fallback (ws too small): simple 2-buffer __syncthreads pipeline
    for (int kt = 0; kt < NK; ++kt) {
      __syncthreads();
      {
#pragma unroll
        for (int i = 0; i < 2; ++i) {
          const float* xf = (const float*)xsrc +
              (size_t)(mblk * 64 + i * 32 + r0) * K_DIM + (size_t)kt * BK +
              (scol >> 1);
          float4 v0 = *(const float4*)(xf);
          float4 v1 = *(const float4*)(xf + 4);
          uint4 pk = make_uint4(f2b_bits(v0.x) | (f2b_bits(v0.y) << 16),
                                f2b_bits(v0.z) | (f2b_bits(v0.w) << 16),
                                f2b_bits(v1.x) | (f2b_bits(v1.y) << 16),
                                f2b_bits(v1.z) | (f2b_bits(v1.w) << 16));
          *(uint4*)(lds + AOFF(kt & 1) + (size_t)(i * 32 + r0) * 128 +
                    (scol ^ swz0)) = pk;
        }
        uint4 pa = *(const uint4*)(wqb + (size_t)(n0 + r0) * 8192 +
                                   (size_t)kt * 128 + scol);
        uint4 pb = *(const uint4*)(wqb + (size_t)(n0 + 32 + r0) * 8192 +
                                   (size_t)kt * 128 + scol);
        *(bf16x8*)(lds + BOFF(kt & 1) + bwr0) = decode8(pa);
        *(bf16x8*)(lds + BOFF(kt & 1) + bwr1) = decode8(pb);
      }
      __syncthreads();
      COMPUTE(kt & 1);
    }
  }

  // ---- epilogue: scale, bias, exact GELU ----
#pragma unroll
  for (int c = 0; c < 2; ++c) {
    const int ngc = n0 + nh * 32 + c * 16 + l16;
    const float s  = scale[ngc];
    const float bb = bias[ngc];
    f32x4 v0 = c ? acc01 : acc00;
    f32x4 v1 = c ? acc11 : acc10;
#pragma unroll
    for (int fr = 0; fr < 2; ++fr) {
      f32x4 vv = fr ? v1 : v0;
#pragma unroll
      for (int j = 0; j < 4; ++j) {
        int m = mblk * 64 + mq2 * 32 + fr * 16 + lq * 4 + j;
        float y = vv[j] * s + bb;
        float g = 0.5f * y * (1.0f + erff(y * 0.70710678118654752f));
        out[(size_t)m * N_DIM + ngc] = g;
      }
    }
  }
#undef ISSUE_A
#undef ISSUE_B
#undef DECODE_B
#undef WAITV
#undef BARRIER
#undef COMPUTE
#undef BODY
}

extern "C" void kernel_launch(void* const* d_in, const int* in_sizes, int n_in,
                              void* d_out, int out_size, void* d_ws, size_t ws_size,
                              hipStream_t stream) {
  const float* x     = (const float*)d_in[0];
  const int*   wq    = (const int*)d_in[1];
  const float* scale = (const float*)d_in[2];
  const float* bias  = (const float*)d_in[3];
  float* out = (float*)d_out;

  const size_t xb_bytes = (size_t)M_DIM * K_DIM * 2;   // 1 MB
  if (ws_size >= xb_bytes) {
    ushort_t* xb = (ushort_t*)d_ws;
    convert_x_kernel<<<(M_DIM * K_DIM) / (256 * 4), 256, 0, stream>>>(x, xb);
    fp4gemm_kernel<true><<<NBLK, NT, 0, stream>>>(xb, wq, scale, bias, out);
  } else {
    fp4gemm_kernel<false><<<NBLK, NT, 0, stream>>>(x, wq, scale, bias, out);
  }
}

// Round 9
// 43.261 us; speedup vs baseline: 1.0380x; 1.0380x over previous
//
#include <hip/hip_runtime.h>
#include <stdint.h>

// FusedFP4Linear: out = gelu(x @ dequant(w_fp4)^T + bias)
// M=128, K=4096, N=16384. Weights [N, K/2] int32, low byte = two FP4 nibbles
// (hi nibble = even k, lo nibble = odd k).
// R9: split-K/2. Grid 512 = 256 n-tiles x 2 k-halves; block = 128x64 out,
// 8 waves, 32 k-tiles. LDS 72KB (A x3 + B x3 bufs) -> 2 blocks/CU = 4
// waves/SIMD, two independent barrier chains overlap each other's stalls.
// Exact FIFO-derived counted vmcnt (steady 3; A(k) retirement GUARANTEED,
// fixing R5/R8 off-by-N). fp32 partials in ws + streaming reduce+GELU pass.

#define M_DIM 128
#define K_DIM 4096
#define N_DIM 16384
#define BK    64
#define KTH   32               // k-tiles per block (K/2 / 64)
#define NT    512              // 8 waves
#define NBLK_G 512

#define A3OFF(i) ((i)*16384)            // 3 x 16KB A buffers
#define B3OFF(i) (49152 + (i)*8192)     // 3 x 8KB decoded-B buffers
#define LDS_SZ   73728                  // 72KB -> 2 blocks/CU

#define XB_BYTES ((size_t)M_DIM*K_DIM*2)        // 1 MB
#define MN       ((size_t)M_DIM*N_DIM)          // 2,097,152
#define PART_BYTES (2*MN*4)                     // 16 MB

typedef __attribute__((ext_vector_type(8))) __bf16 bf16x8;
typedef __attribute__((ext_vector_type(4))) float  f32x4;
typedef unsigned short ushort_t;

__device__ __forceinline__ unsigned f2b_bits(float f) {
  unsigned u = __builtin_bit_cast(unsigned, f);
  u += 0x7FFFu + ((u >> 16) & 1u);   // RNE
  return u >> 16;
}

__global__ __launch_bounds__(256) void convert_x_kernel(
    const float* __restrict__ x, ushort_t* __restrict__ xb) {
  int i = (blockIdx.x * blockDim.x + threadIdx.x) * 4;
  float4 v = *(const float4*)(x + i);
  ushort4 p;
  p.x = (ushort_t)f2b_bits(v.x);
  p.y = (ushort_t)f2b_bits(v.y);
  p.z = (ushort_t)f2b_bits(v.z);
  p.w = (ushort_t)f2b_bits(v.w);
  *(ushort4*)(xb + i) = p;
}

__device__ __forceinline__ void gl16(const void* g, void* l) {
  __builtin_amdgcn_global_load_lds(
      (const __attribute__((address_space(1))) void*)g,
      (__attribute__((address_space(3))) void*)l, 16, 0, 0);
}

// 4 packed int32 (low bytes) -> 8 bf16 (k-order: b0.hi, b0.lo, b1.hi, ...)
__device__ __forceinline__ bf16x8 decode8(uint4 p) {
  unsigned u01 = __builtin_amdgcn_perm(p.y, p.x, 0x04000400u);
  unsigned u23 = __builtin_amdgcn_perm(p.w, p.z, 0x04000400u);
  unsigned q   = __builtin_amdgcn_perm(u23, u01, 0x05040100u);  // [x0,y0,z0,w0]
  unsigned e  = (q >> 4) & 0x0F0F0F0Fu;
  unsigned o  = q & 0x0F0F0F0Fu;
  unsigned em = e & 0x07070707u, om = o & 0x07070707u;
  unsigned elo = __builtin_amdgcn_perm(0xC0804000u, 0xC0800000u, em);
  unsigned ehi = __builtin_amdgcn_perm(0x40404040u, 0x3F3F3F00u, em);
  unsigned olo = __builtin_amdgcn_perm(0xC0804000u, 0xC0800000u, om);
  unsigned ohi = __builtin_amdgcn_perm(0x40404040u, 0x3F3F3F00u, om);
  ehi |= (e & 0x08080808u) << 4;
  ohi |= (o & 0x08080808u) << 4;
  unsigned t0 = __builtin_amdgcn_perm(ehi, elo, 0x05010400u);
  unsigned t1 = __builtin_amdgcn_perm(ohi, olo, 0x05010400u);
  unsigned t2 = __builtin_amdgcn_perm(ehi, elo, 0x07030602u);
  unsigned t3 = __builtin_amdgcn_perm(ohi, olo, 0x07030602u);
  uint4 r;
  r.x = __builtin_amdgcn_perm(t1, t0, 0x05040100u);
  r.y = __builtin_amdgcn_perm(t1, t0, 0x07060302u);
  r.z = __builtin_amdgcn_perm(t3, t2, 0x05040100u);
  r.w = __builtin_amdgcn_perm(t3, t2, 0x07060302u);
  return __builtin_bit_cast(bf16x8, r);
}

#define MFMA16(a_, b_, c_) __builtin_amdgcn_mfma_f32_16x16x32_bf16(a_, b_, c_, 0, 0, 0)

__global__ __launch_bounds__(NT, 4) void fp4gemm_split_kernel(
    const ushort_t* __restrict__ xsrc,    // bf16 x [128,4096]
    const int*  __restrict__ wq,          // [N, K/2] packed
    float* __restrict__ partial) {        // [2, M, N] fp32
  __shared__ __align__(16) uint8_t lds[LDS_SZ];

  const int t   = threadIdx.x;
  const int w   = t >> 6;                 // wave 0..7
  const int l   = t & 63;
  const int l16 = l & 15;
  const int lq  = l >> 4;
  const int mq  = w >> 1;                 // 0..3: rows mq*32..+31
  const int nh  = w & 1;                  // 0..1: cols nh*32..+31

  // bid -> (xcd = bid&7, n_idx = (bid&7)*32 + (bid>>4), khalf = (bid>>3)&1)
  // bijective; both k-halves of an n-tile land on the same XCD (A via L2).
  const int bid   = blockIdx.x;
  const int n0    = ((bid & 7) * 32 + (bid >> 4)) * 64;
  const int khalf = (bid >> 3) & 1;
  const int kgB   = khalf * KTH;          // global k-tile base

  // staging geometry: 512 thr x 16B = 8KB = 64 rows x 128B per gl16 round
  const int srow = t >> 3;                // 0..63
  const int scol = (t & 7) * 16;          // byte col 0..112
  const int sswz = (srow & 7) << 4;
  const int scbs = scol ^ sswz;           // pre-swizzled A source col
  const int bwr  = srow * 128 + (scol ^ sswz);   // B decoded LDS write off

  const uint8_t* xb  = (const uint8_t*)xsrc;  // bf16 row = 8192 B
  const uint8_t* wqb = (const uint8_t*)wq;    // int32 row = 8192 B

  uint4 rq0, rq1, rq2, rq3;               // B packed reg slots (mod 4)

#define ISSUE_A(k_, u3_) do { \
  gl16(xb + (size_t)(srow) * 8192 + (size_t)(kgB + (k_)) * 128 + scbs, \
       lds + A3OFF(u3_) + w * 1024); \
  gl16(xb + (size_t)(64 + srow) * 8192 + (size_t)(kgB + (k_)) * 128 + scbs, \
       lds + A3OFF(u3_) + 8192 + w * 1024); \
} while (0)

#define ISSUE_B(k_, s_) do { \
  rq##s_ = *(const uint4*)(wqb + (size_t)(n0 + srow) * 8192 + \
                           (size_t)(kgB + (k_)) * 128 + scol); \
} while (0)

#define DECODE_B(s_, u3_) do { \
  *(bf16x8*)(lds + B3OFF(u3_) + bwr) = decode8(rq##s_); \
} while (0)

#define WAITV(N_) asm volatile("s_waitcnt vmcnt(" #N_ ")" ::: "memory")
#define BARRIER() do { \
  asm volatile("s_waitcnt lgkmcnt(0)" ::: "memory"); \
  __builtin_amdgcn_s_barrier(); \
  __builtin_amdgcn_sched_barrier(0); \
} while (0)

  f32x4 acc00 = {0,0,0,0}, acc01 = {0,0,0,0};
  f32x4 acc10 = {0,0,0,0}, acc11 = {0,0,0,0};

  const int aR0 = (mq * 32 + l16) * 128;       // +2048 for fr=1
  const int bR0 = (nh * 32 + l16) * 128;       // +2048 for c=1
  const int cB  = (lq << 4) ^ ((l16 & 7) << 4);

#define COMPUTE(c3_) do { \
  const uint8_t* Ab_ = lds + A3OFF(c3_); \
  const uint8_t* Bb_ = lds + B3OFF(c3_); \
  _Pragma("unroll") \
  for (int ks_ = 0; ks_ < 2; ++ks_) { \
    const int cS_ = (ks_ << 6) ^ cB; \
    bf16x8 a0_ = *(const bf16x8*)(Ab_ + aR0 + cS_); \
    bf16x8 a1_ = *(const bf16x8*)(Ab_ + aR0 + 2048 + cS_); \
    bf16x8 b0_ = *(const bf16x8*)(Bb_ + bR0 + cS_); \
    bf16x8 b1_ = *(const bf16x8*)(Bb_ + bR0 + 2048 + cS_); \
    acc00 = MFMA16(a0_, b0_, acc00); \
    acc01 = MFMA16(a0_, b1_, acc01); \
    acc10 = MFMA16(a1_, b0_, acc10); \
    acc11 = MFMA16(a1_, b1_, acc11); \
  } \
} while (0)

// Steady body k: WAITV(3) retires A(k) (newer: B(k+5), A(k+1)x2 = exactly 3).
// Tile k lives in (A3[k%3], B3[k%3]); body k decodes tile k+2 and issues
// A(k+2), B(k+6).  s4_=(k+2)&3, u3_=(k+2)%3, c3_=k%3.
#define BODY_S(k_, s4_, u3_, c3_) do { \
  WAITV(3); \
  BARRIER(); \
  DECODE_B(s4_, u3_); \
  ISSUE_B((k_) + 6, s4_); \
  ISSUE_A((k_) + 2, u3_); \
  COMPUTE(c3_); \
} while (0)

#define GROUP12(k0_) do { \
  BODY_S((k0_)+0, 0,1,2); BODY_S((k0_)+1, 1,2,0); BODY_S((k0_)+2, 2,0,1); \
  BODY_S((k0_)+3, 3,1,2); BODY_S((k0_)+4, 0,2,0); BODY_S((k0_)+5, 1,0,1); \
  BODY_S((k0_)+6, 2,1,2); BODY_S((k0_)+7, 3,2,0); BODY_S((k0_)+8, 0,0,1); \
  BODY_S((k0_)+9, 1,1,2); BODY_S((k0_)+10,2,2,0); BODY_S((k0_)+11,3,0,1); \
} while (0)

  // ---- prologue (FIFO trace: exact) ----
  ISSUE_B(0, 0); ISSUE_B(1, 1); ISSUE_B(2, 2); ISSUE_B(3, 3);   // 4 ops
  ISSUE_A(0, 0); ISSUE_A(1, 1);                                 // 4 ops
  WAITV(4);                      // B0..B3 retired (A0,A1 may fly)
  DECODE_B(0, 0); DECODE_B(1, 1);
  ISSUE_B(4, 0); ISSUE_B(5, 1);  // outstanding: A0ab A1ab B4 B5 = 6
  // k=0: retire A0ab -> newer = A1ab,B4,B5 ... FIFO: A0a,A0b,A1a,A1b,B4,B5 -> 4
  WAITV(4); BARRIER();
  DECODE_B(2, 2); ISSUE_B(6, 2); ISSUE_A(2, 2); COMPUTE(0);
  // k=1: FIFO: A1a,A1b,B4,B5,B6,A2a,A2b -> newer than A1b = 5
  WAITV(5); BARRIER();
  DECODE_B(3, 0); ISSUE_B(7, 3); ISSUE_A(3, 0); COMPUTE(1);
  // ---- steady: k = 2..25 (2 x 12, period lcm(3,4)=12) ----
  GROUP12(2);
  GROUP12(14);
  // ---- tail (k = 26..31; no B issue past 31, no A past 31) ----
  WAITV(3); BARRIER(); DECODE_B(0, 1); ISSUE_A(28, 1); COMPUTE(2);  // k=26
  WAITV(2); BARRIER(); DECODE_B(1, 2); ISSUE_A(29, 2); COMPUTE(0);  // k=27
  WAITV(2); BARRIER(); DECODE_B(2, 0); ISSUE_A(30, 0); COMPUTE(1);  // k=28
  WAITV(2); BARRIER(); DECODE_B(3, 1); ISSUE_A(31, 1); COMPUTE(2);  // k=29
  WAITV(2); BARRIER(); COMPUTE(0);                                  // k=30
  WAITV(0); BARRIER(); COMPUTE(1);                                  // k=31

  // ---- store fp32 partials ----
  float* pk = partial + (size_t)khalf * MN;
#pragma unroll
  for (int c = 0; c < 2; ++c) {
    const int ngc = n0 + nh * 32 + c * 16 + l16;
    f32x4 v0 = c ? acc01 : acc00;
    f32x4 v1 = c ? acc11 : acc10;
#pragma unroll
    for (int fr = 0; fr < 2; ++fr) {
      f32x4 vv = fr ? v1 : v0;
#pragma unroll
      for (int j = 0; j < 4; ++j) {
        int m = mq * 32 + fr * 16 + lq * 4 + j;
        pk[(size_t)m * N_DIM + ngc] = vv[j];
      }
    }
  }
#undef ISSUE_A
#undef ISSUE_B
#undef DECODE_B
#undef WAITV
#undef BARRIER
#undef COMPUTE
#undef BODY_S
#undef GROUP12
}

__global__ __launch_bounds__(256) void reduce_gelu_kernel(
    const float* __restrict__ partial,    // [2, M, N]
    const float* __restrict__ scale,      // [N]
    const float* __restrict__ bias,       // [N]
    float* __restrict__ out) {            // [M, N]
  size_t idx = ((size_t)blockIdx.x * 256 + threadIdx.x) * 4;
  float4 a = *(const float4*)(partial + idx);
  float4 b = *(const float4*)(partial + MN + idx);
  int n = (int)(idx & (N_DIM - 1));
  float4 s  = *(const float4*)(scale + n);
  float4 bb = *(const float4*)(bias + n);
  float4 r;
  {
    float y;
    y = (a.x + b.x) * s.x + bb.x; r.x = 0.5f * y * (1.0f + erff(y * 0.70710678118654752f));
    y = (a.y + b.y) * s.y + bb.y; r.y = 0.5f * y * (1.0f + erff(y * 0.70710678118654752f));
    y = (a.z + b.z) * s.z + bb.z; r.z = 0.5f * y * (1.0f + erff(y * 0.70710678118654752f));
    y = (a.w + b.w) * s.w + bb.w; r.w = 0.5f * y * (1.0f + erff(y * 0.70710678118654752f));
  }
  *(float4*)(out + idx) = r;
}

// Fallback (ws too small): full-K, fp32-x inline, simple 2-buffer pipeline.
__global__ __launch_bounds__(NT) void fp4gemm_fallback_kernel(
    const float* __restrict__ x, const int* __restrict__ wq,
    const float* __restrict__ scale, const float* __restrict__ bias,
    float* __restrict__ out) {
  __shared__ __align__(16) uint8_t lds[LDS_SZ];
  const int t = threadIdx.x, w = t >> 6, l = t & 63;
  const int l16 = l & 15, lq = l >> 4, mq = w >> 1, nh = w & 1;
  const int n0 = (int)blockIdx.x * 64;
  const int srow = t >> 3, scol = (t & 7) * 16, sswz = (srow & 7) << 4;
  const int bwr = srow * 128 + (scol ^ sswz);
  const uint8_t* wqb = (const uint8_t*)wq;
  f32x4 acc00 = {0,0,0,0}, acc01 = {0,0,0,0};
  f32x4 acc10 = {0,0,0,0}, acc11 = {0,0,0,0};
  const int aR0 = (mq * 32 + l16) * 128;
  const int bR0 = (nh * 32 + l16) * 128;
  const int cB  = (lq << 4) ^ ((l16 & 7) << 4);
  for (int kt = 0; kt < 64; ++kt) {
    __syncthreads();
    int bb = kt & 1;
#pragma unroll
    for (int i = 0; i < 2; ++i) {
      const float* xf = x + (size_t)(i * 64 + srow) * K_DIM + (size_t)kt * BK + (scol >> 1);
      float4 v0 = *(const float4*)(xf);
      float4 v1 = *(const float4*)(xf + 4);
      uint4 pk = make_uint4(f2b_bits(v0.x) | (f2b_bits(v0.y) << 16),
                            f2b_bits(v0.z) | (f2b_bits(v0.w) << 16),
                            f2b_bits(v1.x) | (f2b_bits(v1.y) << 16),
                            f2b_bits(v1.z) | (f2b_bits(v1.w) << 16));
      *(uint4*)(lds + A3OFF(bb) + (size_t)(i * 64 + srow) * 128 + (scol ^ sswz)) = pk;
    }
    {
      uint4 pv = *(const uint4*)(wqb + (size_t)(n0 + srow) * 8192 + (size_t)kt * 128 + scol);
      *(bf16x8*)(lds + B3OFF(bb) + bwr) = decode8(pv);
    }
    __syncthreads();
    {
      const uint8_t* Ab_ = lds + A3OFF(bb);
      const uint8_t* Bb_ = lds + B3OFF(bb);
#pragma unroll
      for (int ks = 0; ks < 2; ++ks) {
        const int cS = (ks << 6) ^ cB;
        bf16x8 a0 = *(const bf16x8*)(Ab_ + aR0 + cS);
        bf16x8 a1 = *(const bf16x8*)(Ab_ + aR0 + 2048 + cS);
        bf16x8 b0 = *(const bf16x8*)(Bb_ + bR0 + cS);
        bf16x8 b1 = *(const bf16x8*)(Bb_ + bR0 + 2048 + cS);
        acc00 = MFMA16(a0, b0, acc00);
        acc01 = MFMA16(a0, b1, acc01);
        acc10 = MFMA16(a1, b0, acc10);
        acc11 = MFMA16(a1, b1, acc11);
      }
    }
  }
#pragma unroll
  for (int c = 0; c < 2; ++c) {
    const int ngc = n0 + nh * 32 + c * 16 + l16;
    const float s = scale[ngc];
    const float bv = bias[ngc];
    f32x4 v0 = c ? acc01 : acc00;
    f32x4 v1 = c ? acc11 : acc10;
#pragma unroll
    for (int fr = 0; fr < 2; ++fr) {
      f32x4 vv = fr ? v1 : v0;
#pragma unroll
      for (int j = 0; j < 4; ++j) {
        int m = mq * 32 + fr * 16 + lq * 4 + j;
        float y = vv[j] * s + bv;
        out[(size_t)m * N_DIM + ngc] =
            0.5f * y * (1.0f + erff(y * 0.70710678118654752f));
      }
    }
  }
}

extern "C" void kernel_launch(void* const* d_in, const int* in_sizes, int n_in,
                              void* d_out, int out_size, void* d_ws, size_t ws_size,
                              hipStream_t stream) {
  const float* x     = (const float*)d_in[0];
  const int*   wq    = (const int*)d_in[1];
  const float* scale = (const float*)d_in[2];
  const float* bias  = (const float*)d_in[3];
  float* out = (float*)d_out;

  if (ws_size >= XB_BYTES + PART_BYTES) {
    ushort_t* xb = (ushort_t*)d_ws;
    float* partial = (float*)((uint8_t*)d_ws + XB_BYTES);
    convert_x_kernel<<<(M_DIM * K_DIM) / (256 * 4), 256, 0, stream>>>(x, xb);
    fp4gemm_split_kernel<<<NBLK_G, NT, 0, stream>>>(xb, wq, partial);
    reduce_gelu_kernel<<<(int)(MN / (256 * 4)), 256, 0, stream>>>(
        partial, scale, bias, out);
  } else {
    fp4gemm_fallback_kernel<<<N_DIM / 64, NT, 0, stream>>>(
        x, wq, scale, bias, out);
  }
}